// Round 17
// baseline (127.159 us; speedup 1.0000x reference)
//
#include <hip/hip_runtime.h>
#include <stdint.h>

constexpr int Bn = 8, Nn = 4096, Sn = 1024, Cc = 64, KNN = 32, C1 = 128, C2 = 256;
constexpr int Qq = Bn * Sn;     // 8192 queries
constexpr int Mm = Qq * KNN;    // 262144 samples
constexpr int OUT_XYZ = Bn * Sn * 3;  // 24576 floats (output 0)
constexpr float BNEPS = 1e-5f;
constexpr unsigned RSEL = 9;    // sample order statistic -> E[candidates]~72

// ---------- ws layout ----------
constexpr size_t SZ_IDX  = (size_t)Qq * KNN * 4;        // 1 MB
constexpr size_t SZ_PTST = (size_t)Bn * Nn * Cc * 2;    // 4 MB (bf16)
constexpr int    NB_MLP  = Mm / 64;                     // 4096 blocks (m2f)
constexpr int    NB_M1   = Mm / 128;                    // 2048 blocks (mlp1s)
constexpr size_t SZ_P1   = (size_t)NB_M1 * 256 * 4;     // 2 MB
constexpr size_t SZ_P2   = (size_t)NB_MLP * 512 * 4;    // 8 MB
constexpr size_t OFF_IDX  = 0;
constexpr size_t OFF_PTST = OFF_IDX + SZ_IDX;
constexpr size_t OFF_P1   = OFF_PTST + SZ_PTST;
constexpr size_t OFF_P2   = OFF_P1 + SZ_P1;
constexpr size_t OFF_P1B  = OFF_P2 + SZ_P2;
constexpr size_t OFF_P2B  = OFF_P1B + (size_t)128 * 256 * 4;
constexpr size_t OFF_BN1  = OFF_P2B + (size_t)128 * 512 * 4;
constexpr size_t OFF_W2F  = OFF_BN1 + 1024;                  // 64 KB
constexpr size_t OFF_W1F  = OFF_W2F + (size_t)32768 * 2;     // 24 KB
constexpr size_t OFF_VAL  = (OFF_W1F + (size_t)12288 * 2 + 255) & ~(size_t)255;  // extreme: 8 MB

typedef __attribute__((ext_vector_type(8))) __bf16 bf16x8;
typedef __attribute__((ext_vector_type(4))) float f32x4;

__device__ __forceinline__ unsigned short f2bf(float f) {
  unsigned u = __float_as_uint(f);
  u = u + 0x7FFFu + ((u >> 16) & 1u);   // RNE
  return (unsigned short)(u >> 16);
}

// ballot-aggregated histogram add (use only for CLUSTERED bins, e.g. fp exponent)
__device__ __forceinline__ void agg_hist(unsigned* hist, unsigned bin, bool valid, int lane) {
  bool todo = valid;
  while (true) {
    unsigned long long bm = __ballot(todo);
    if (bm == 0ull) break;
    int first = __ffsll(bm) - 1;
    unsigned b = (unsigned)__shfl((int)bin, first);
    unsigned long long m = __ballot(todo && bin == b);
    if (lane == first) atomicAdd(&hist[b], (unsigned)__popcll(m));
    if (todo && bin == b) todo = false;
  }
}

// ---------- kNN (blocks < Qq) + fused prep (blocks >= Qq; outputs consumed only by LATER kernels) ----------
// Distance bits replicate the reference evaluation (norms plain mul/add, dot FMA
// chain, (A+B)-2*dot) under `fp contract(off)`. Threshold U heuristic; fast path
// only if 32<=cnt<=256 (superset proof). Rank directly on u64 (key<<32|idx) --
// distinct u64s => distinct ranks, no tie handling needed; order == top_k's
// value-then-lower-index. Fallback: full radix (round-4 proven).
__global__ __launch_bounds__(256) void k_knn(const float* __restrict__ xyz,
                                             const float* __restrict__ nxyz,
                                             int* __restrict__ idxout,
                                             const float* __restrict__ pts,
                                             const float* __restrict__ W1,
                                             const float* __restrict__ W2,
                                             unsigned short* __restrict__ ptsTbf,
                                             float* __restrict__ outdst,
                                             unsigned short* __restrict__ w1f,
                                             unsigned short* __restrict__ w2f) {
  int t = threadIdx.x;
  if (blockIdx.x >= (unsigned)Qq) {          // ---- prep branch ----
    int blk = blockIdx.x - Qq;
    if (blk < 512) {                         // points [B,C,N] f32 -> [B,N,C] bf16
      __shared__ float tile[64][65];
      int b = blk >> 6, n0 = (blk & 63) * 64;
      int cl = t & 63, rw = t >> 6;
#pragma unroll
      for (int i = 0; i < 16; ++i) {
        int c = i * 4 + rw;
        tile[cl][c] = pts[((size_t)b * Cc + c) * Nn + n0 + cl];
      }
      __syncthreads();
#pragma unroll
      for (int i = 0; i < 16; ++i) {
        int nf = i * 4 + rw;
        ptsTbf[((size_t)b * Nn + n0 + nf) * Cc + cl] = f2bf(tile[nf][cl]);
      }
    } else if (blk < 608) {                  // copy new_xyz to output 0
      int i = t + (blk - 512) * 256;
      if (i < OUT_XYZ) outdst[i] = nxyz[i];
    } else if (blk < 656) {                  // W1 -> bf16 B-frags, K pad 96
      int u = t + (blk - 608) * 256;
      int j = u & 7, lane = (u >> 3) & 63, rest = u >> 9;
      int ks = rest % 3, nt = rest / 3;
      int ch = nt * 16 + (lane & 15);
      int k = ks * 32 + (lane >> 4) * 8 + j;
      w1f[u] = (k < 70) ? f2bf(W1[ch * 70 + k]) : (unsigned short)0;
    } else {                                 // W2 -> bf16 B-frags
      int u = t + (blk - 656) * 256;
      int j = u & 7, lane = (u >> 3) & 63, ks = (u >> 9) & 3, ntile = u >> 11;
      int col = ntile * 16 + (lane & 15);
      int k = ks * 32 + (lane >> 4) * 8 + j;
      w2f[u] = f2bf(W2[col * C1 + k]);
    }
    return;
  }
  // ---- knn branch ----
  int q = blockIdx.x, b = q >> 10;
  int lane = t & 63, w = t >> 6;
  const float4* xb4 = reinterpret_cast<const float4*>(xyz + (size_t)b * Nn * 3);
  float qx = nxyz[q * 3 + 0], qy = nxyz[q * 3 + 1], qz = nxyz[q * 3 + 2];
  unsigned key[16];
  {
#pragma clang fp contract(off)
    float sqq = (qx * qx + qy * qy) + qz * qz;
#pragma unroll
    for (int h = 0; h < 2; ++h) {            // 2 half-chunks of 8 points
      float fl[24];
#pragma unroll
      for (int j = 0; j < 6; ++j) {
        float4 v = xb4[t * 12 + h * 6 + j];
        fl[4 * j + 0] = v.x; fl[4 * j + 1] = v.y; fl[4 * j + 2] = v.z; fl[4 * j + 3] = v.w;
      }
#pragma unroll
      for (int i = 0; i < 8; ++i) {
        float xl = fl[3 * i], yl = fl[3 * i + 1], zl = fl[3 * i + 2];
        float sqp = (xl * xl + yl * yl) + zl * zl;
        float dot = __builtin_fmaf(qz, zl, __builtin_fmaf(qy, yl, qx * xl));
        float d = (sqq + sqp) - 2.0f * dot;
        unsigned u = __float_as_uint(d);
        key[h * 8 + i] = (u & 0x80000000u) ? ~u : (u | 0x80000000u);   // monotone map
      }
    }
  }
  __shared__ unsigned long long buf64[256];
  __shared__ unsigned hist[256];
  __shared__ unsigned hist2[256];
  __shared__ unsigned wsum[4];
  __shared__ unsigned sel_bin, sel_off, cnt, ovf, thrU;
  __shared__ unsigned eqcnt;
  __shared__ int eqbuf[128];

  unsigned s0 = key[0], s1 = key[8];   // samples: points 16t and 16t+8
  hist[t] = 0;
  hist2[t] = 0;
  if (t == 0) { cnt = 0; ovf = 0; thrU = 0xFFFFFFFFu; }
  __syncthreads();
  // S1: top byte of samples (exponent-clustered -> aggregated adds)
  agg_hist(hist, s0 >> 24, true, lane);
  agg_hist(hist, s1 >> 24, true, lane);
  __syncthreads();
  {
    unsigned h = hist[t], v = h;
#pragma unroll
    for (int off = 1; off < 64; off <<= 1) {
      unsigned o = __shfl_up(v, off);
      if (lane >= off) v += o;
    }
    if (lane == 63) wsum[w] = v;
    __syncthreads();
    unsigned woff = 0;
    for (int ww = 0; ww < w; ++ww) woff += wsum[ww];
    v += woff;
    unsigned vex = v - h;
    if (vex < RSEL && RSEL <= v) { sel_bin = (unsigned)t; sel_off = RSEL - vex; }
    __syncthreads();
  }
  unsigned sbin = sel_bin, srem = sel_off;
  // S2: byte 2 of samples in sbin (uniform bins -> plain atomics)
  if ((s0 >> 24) == sbin) atomicAdd(&hist2[(s0 >> 16) & 255u], 1u);
  if ((s1 >> 24) == sbin) atomicAdd(&hist2[(s1 >> 16) & 255u], 1u);
  __syncthreads();
  {
    unsigned h = hist2[t], v = h;
#pragma unroll
    for (int off = 1; off < 64; off <<= 1) {
      unsigned o = __shfl_up(v, off);
      if (lane >= off) v += o;
    }
    if (lane == 63) wsum[w] = v;
    __syncthreads();
    unsigned woff = 0;
    for (int ww = 0; ww < w; ++ww) woff += wsum[ww];
    v += woff;
    unsigned vex = v - h;
    if (vex < srem && srem <= v) {
      unsigned p16 = (sbin << 8) | (unsigned)t;
      thrU = (p16 >= 0xFFFFu) ? 0xFFFFFFFFu : ((p16 + 1u) << 16);
    }
    __syncthreads();
  }
  unsigned U = thrU;
  // compact candidates (key < U), ballot-aggregated
#pragma unroll
  for (int i = 0; i < 16; ++i) {
    bool take = key[i] < U;
    unsigned long long m = __ballot(take);
    if (m == 0ull) continue;
    unsigned base = 0;
    if (lane == 0) base = atomicAdd(&cnt, (unsigned)__popcll(m));
    base = (unsigned)__shfl((int)base, 0);
    if (take) {
      unsigned off = base + (unsigned)__popcll(m & ((1ull << lane) - 1ull));
      if (off < 256u)
        buf64[off] = ((unsigned long long)key[i] << 32) | (unsigned)(t * 16 + i);
      else
        ovf = 1;
    }
  }
  __syncthreads();
  unsigned ncnt = cnt;
  if (!ovf && ncnt >= (unsigned)KNN && ncnt <= 256u) {
    int nc = (int)ncnt;
    if (nc <= 64) {
      // 4-way wave-split u64 rank: candidate = lane; wave w scans lanes [16w,16w+16)
      unsigned long long my64 = (lane < nc) ? buf64[lane] : ~0ull;
      unsigned mylo = (unsigned)my64, myhi = (unsigned)(my64 >> 32);
      int partial = 0;
      int base = w * 16;
#pragma unroll
      for (int ii = 0; ii < 16; ++ii) {
        int i = base + ii;
        unsigned olo = (unsigned)__builtin_amdgcn_readlane((int)mylo, i);
        unsigned ohi = (unsigned)__builtin_amdgcn_readlane((int)myhi, i);
        unsigned long long o = ((unsigned long long)ohi << 32) | olo;
        partial += (i < nc && o < my64);
      }
      hist[t] = (unsigned)partial;   // t == w*64+lane
      __syncthreads();
      if (t < nc) {
        int r = (int)(hist[t] + hist[64 + t] + hist[128 + t] + hist[192 + t]);
        if (r < KNN) idxout[q * KNN + r] = (int)(unsigned)(buf64[t] & 0xFFFFFFFFull);
      }
    } else if (nc <= 128) {
      // 2-way split: candidate = t&127; half t>>7 scans its 64-chunk
      int cid = t & 127;
      unsigned long long my64 = (cid < nc) ? buf64[cid] : ~0ull;
      int c = t >> 7;
      int ci = c * 64 + lane;
      unsigned long long ch64 = (ci < nc) ? buf64[ci] : ~0ull;
      unsigned clo = (unsigned)ch64, chi = (unsigned)(ch64 >> 32);
      int partial = 0;
      if (c * 64 < nc) {
#pragma unroll
        for (int i = 0; i < 64; ++i) {
          unsigned olo = (unsigned)__builtin_amdgcn_readlane((int)clo, i);
          unsigned ohi = (unsigned)__builtin_amdgcn_readlane((int)chi, i);
          unsigned long long o = ((unsigned long long)ohi << 32) | olo;
          partial += (o < my64);
        }
      }
      hist[t] = (unsigned)partial;
      __syncthreads();
      if (t < nc) {
        int r = (int)(hist[t] + hist[t + 128]);
        if (r < KNN) idxout[q * KNN + r] = (int)(unsigned)(buf64[t] & 0xFFFFFFFFull);
      }
    } else {
      // full: candidate = t, scan all chunks (rare)
      unsigned long long my64 = (t < nc) ? buf64[t] : ~0ull;
      int r = 0;
      int nchunk = (nc + 63) >> 6;
      for (int c = 0; c < nchunk; ++c) {
        int ci = c * 64 + lane;
        unsigned long long v = (ci < nc) ? buf64[ci] : ~0ull;
        unsigned vlo = (unsigned)v, vhi = (unsigned)(v >> 32);
#pragma unroll
        for (int i = 0; i < 64; ++i) {
          unsigned olo = (unsigned)__builtin_amdgcn_readlane((int)vlo, i);
          unsigned ohi = (unsigned)__builtin_amdgcn_readlane((int)vhi, i);
          unsigned long long o = ((unsigned long long)ohi << 32) | olo;
          r += (o < my64);
        }
      }
      if (t < nc && r < KNN) idxout[q * KNN + r] = (int)(unsigned)(buf64[t] & 0xFFFFFFFFull);
    }
  } else {
    // fallback: full 4-pass radix (round-4 proven path)
    unsigned prefix = 0, remaining = (unsigned)KNN;
    if (t == 0) { cnt = 0; eqcnt = 0; }
#pragma unroll
    for (int shift = 24; shift >= 0; shift -= 8) {
      hist[t] = 0;
      __syncthreads();
      unsigned himask = (shift == 24) ? 0u : (0xFFFFFFFFu << ((shift + 8) & 31));
#pragma unroll
      for (int i = 0; i < 16; ++i)
        if ((key[i] & himask) == prefix)
          atomicAdd(&hist[(key[i] >> shift) & 255], 1u);
      __syncthreads();
      unsigned h = hist[t], v = h;
#pragma unroll
      for (int off = 1; off < 64; off <<= 1) {
        unsigned o = __shfl_up(v, off);
        if (lane >= off) v += o;
      }
      if (lane == 63) wsum[w] = v;
      __syncthreads();
      unsigned woff = 0;
      for (int ww = 0; ww < w; ++ww) woff += wsum[ww];
      v += woff;
      unsigned vex = v - h;
      if (vex < remaining && remaining <= v) { sel_bin = (unsigned)t; sel_off = vex; }
      __syncthreads();
      prefix |= sel_bin << shift;
      remaining -= sel_off;
    }
#pragma unroll
    for (int i = 0; i < 16; ++i) {
      int p = t * 16 + i;
      if (key[i] < prefix) {
        unsigned pos = atomicAdd(&cnt, 1u);
        idxout[q * KNN + pos] = p;
      } else if (key[i] == prefix) {
        unsigned e = atomicAdd(&eqcnt, 1u);
        if (e < 128u) eqbuf[e] = p;
      }
    }
    __syncthreads();
    if (t == 0) {
      int n = (int)min(eqcnt, 128u);
      for (int a = 1; a < n; ++a) {
        int x = eqbuf[a], bi = a - 1;
        while (bi >= 0 && eqbuf[bi] > x) { eqbuf[bi + 1] = eqbuf[bi]; --bi; }
        eqbuf[bi + 1] = x;
      }
      int base = (int)cnt;
      for (int j = 0; j < (int)remaining; ++j) idxout[q * KNN + base + j] = eqbuf[j];
    }
  }
}

// ---------- staging: 64-row gather tile -> zs (swz (j&7)<<4), 4 loaders/row ----------
__device__ __forceinline__ void stage_gather(unsigned short* zs,
                                             const unsigned short* __restrict__ ptsTbf,
                                             const float* __restrict__ xyz,
                                             const float* __restrict__ nxyz,
                                             const int* __restrict__ idx,
                                             int m0, int b, int t) {
  int j = t >> 2, part = t & 3;
  int m = m0 + j;
  int pid = idx[m];
  const uint4* src =
      reinterpret_cast<const uint4*>(ptsTbf + ((size_t)b * Nn + pid) * Cc + part * 16);
  char* zc = reinterpret_cast<char*>(zs);
  int base = j * 256, swz = (j & 7) << 4;
  uint4 s0 = src[0], s1 = src[1];
  *reinterpret_cast<uint4*>(zc + ((base + part * 32) ^ swz)) = s0;
  *reinterpret_cast<uint4*>(zc + ((base + part * 32 + 16) ^ swz)) = s1;
  uint4 ex = make_uint4(0u, 0u, 0u, 0u);
  if (part == 0) {
    const float* xp = xyz + ((size_t)b * Nn + pid) * 3;
    int s = (m >> 5) & (Sn - 1);
    const float* qp = nxyz + (size_t)(b * Sn + s) * 3;
    ex.x = (unsigned)f2bf(xp[0]) | ((unsigned)f2bf(xp[1]) << 16);
    ex.y = (unsigned)f2bf(xp[2]) | ((unsigned)f2bf(qp[0]) << 16);
    ex.z = (unsigned)f2bf(qp[1]) | ((unsigned)f2bf(qp[2]) << 16);
  }
  *reinterpret_cast<uint4*>(zc + ((base + (8 + part) * 16) ^ swz)) = ex;
}

// ---------- staging: 128-row gather tile, 2 loaders/row ----------
__device__ __forceinline__ void stage_gather128(unsigned short* zs,
                                                const unsigned short* __restrict__ ptsTbf,
                                                const float* __restrict__ xyz,
                                                const float* __restrict__ nxyz,
                                                const int* __restrict__ idx,
                                                int m0, int b, int t) {
  int j = t >> 1, part = t & 1;
  int m = m0 + j;
  int pid = idx[m];
  const uint4* src =
      reinterpret_cast<const uint4*>(ptsTbf + ((size_t)b * Nn + pid) * Cc + part * 32);
  char* zc = reinterpret_cast<char*>(zs);
  int base = j * 256, swz = (j & 7) << 4;
#pragma unroll
  for (int u = 0; u < 4; ++u)
    *reinterpret_cast<uint4*>(zc + ((base + part * 64 + u * 16) ^ swz)) = src[u];
  if (part == 0) {
    uint4 ex = make_uint4(0u, 0u, 0u, 0u);
    const float* xp = xyz + ((size_t)b * Nn + pid) * 3;
    int s = (m >> 5) & (Sn - 1);
    const float* qp = nxyz + (size_t)(b * Sn + s) * 3;
    ex.x = (unsigned)f2bf(xp[0]) | ((unsigned)f2bf(xp[1]) << 16);
    ex.y = (unsigned)f2bf(xp[2]) | ((unsigned)f2bf(qp[0]) << 16);
    ex.z = (unsigned)f2bf(qp[1]) | ((unsigned)f2bf(qp[2]) << 16);
    *reinterpret_cast<uint4*>(zc + ((base + 128) ^ swz)) = ex;
    uint4 z0 = make_uint4(0u, 0u, 0u, 0u);
    *reinterpret_cast<uint4*>(zc + ((base + 144) ^ swz)) = z0;
  } else {
    uint4 z0 = make_uint4(0u, 0u, 0u, 0u);
    *reinterpret_cast<uint4*>(zc + ((base + 160) ^ swz)) = z0;
    *reinterpret_cast<uint4*>(zc + ((base + 176) ^ swz)) = z0;
  }
}

// ---------- layer1 stats-only (128-row tile): gather + W1 MFMA -> sum/sumsq partials ----------
__global__ __launch_bounds__(256) void k_mlp1s(const unsigned short* __restrict__ ptsTbf,
                                               const float* __restrict__ xyz,
                                               const float* __restrict__ nxyz,
                                               const int* __restrict__ idx,
                                               const unsigned short* __restrict__ w1f,
                                               const float* __restrict__ b1,
                                               float* __restrict__ part1) {
  __shared__ unsigned short zs[128 * 128];   // 32 KB
  int t = threadIdx.x;
  int m0 = blockIdx.x * 128;
  int b = m0 >> 15;
  int lane = t & 63, w = t >> 6;
  bf16x8 bfrag[2][3];
  {
    const uint4* wp = reinterpret_cast<const uint4*>(w1f);
#pragma unroll
    for (int nt = 0; nt < 2; ++nt)
#pragma unroll
      for (int ks = 0; ks < 3; ++ks)
        bfrag[nt][ks] = __builtin_bit_cast(bf16x8, wp[((w * 2 + nt) * 3 + ks) * 64 + lane]);
  }
  stage_gather128(zs, ptsTbf, xyz, nxyz, idx, m0, b, t);
  __syncthreads();
  f32x4 acc[8][2];
#pragma unroll
  for (int mt = 0; mt < 8; ++mt)
#pragma unroll
    for (int nt = 0; nt < 2; ++nt) acc[mt][nt] = f32x4{0.f, 0.f, 0.f, 0.f};
  int r15 = lane & 15, rhi = lane >> 4;
  const char* zc = reinterpret_cast<const char*>(zs);
#pragma unroll
  for (int mt = 0; mt < 8; ++mt) {
    int row = mt * 16 + r15;
    bf16x8 af[3];
#pragma unroll
    for (int ks = 0; ks < 3; ++ks)
      af[ks] = __builtin_bit_cast(
          bf16x8, *reinterpret_cast<const uint4*>(
                      zc + ((row * 256 + ks * 64 + rhi * 16) ^ ((row & 7) << 4))));
#pragma unroll
    for (int nt = 0; nt < 2; ++nt)
#pragma unroll
      for (int ks = 0; ks < 3; ++ks)
        acc[mt][nt] =
            __builtin_amdgcn_mfma_f32_16x16x32_bf16(af[ks], bfrag[nt][ks], acc[mt][nt], 0, 0, 0);
  }
#pragma unroll
  for (int nt = 0; nt < 2; ++nt) {
    int col = w * 32 + nt * 16 + r15;
    float bv = b1[col];
    float s = 0.f, ss = 0.f;
#pragma unroll
    for (int mt = 0; mt < 8; ++mt)
#pragma unroll
      for (int rg = 0; rg < 4; ++rg) {
        float v = acc[mt][nt][rg] + bv;
        s += v; ss += v * v;
      }
    s += __shfl_xor(s, 16); s += __shfl_xor(s, 32);
    ss += __shfl_xor(ss, 16); ss += __shfl_xor(ss, 32);
    if (lane < 16) {
      part1[(size_t)blockIdx.x * 256 + col] = s;
      part1[(size_t)blockIdx.x * 256 + 128 + col] = ss;
    }
  }
}

// ---------- stats reduce (layer1) ----------
__global__ __launch_bounds__(256) void k_red1a(const float* __restrict__ part1,
                                               float* __restrict__ p1b) {
  int t = threadIdx.x, r = blockIdx.x;       // 128 blocks x 16 rows
  float acc = 0.f;
  for (int row = r * 16; row < r * 16 + 16; ++row)
    acc += part1[(size_t)row * 256 + t];
  p1b[r * 256 + t] = acc;
}
// bn1[t] = a; bn1[128+t] = a*b1 + be1 - mean*a  (b1 folded so fused kernel skips it)
__global__ __launch_bounds__(256) void k_red1b(const float* __restrict__ p1b,
                                               const float* __restrict__ b1,
                                               const float* __restrict__ g1,
                                               const float* __restrict__ be1,
                                               float* __restrict__ bn1) {
  __shared__ float lds[256];
  int t = threadIdx.x;
  float acc = 0.f;
  for (int row = 0; row < 128; ++row) acc += p1b[row * 256 + t];
  lds[t] = acc;
  __syncthreads();
  if (t < 128) {
    float sum = lds[t], ss = lds[128 + t];
    float mean = sum / (float)Mm;
    float var = ss / (float)Mm - mean * mean;
    float a = g1[t] * rsqrtf(var + BNEPS);
    bn1[t] = a;
    bn1[128 + t] = a * b1[t] + (be1[t] - mean * a);
  }
}

// ---------- fused layer1+layer2: gather -> W1 MFMA -> BN1+relu -> W2 MFMA -> stats+extreme ----------
__global__ __launch_bounds__(256) void k_m2f(const unsigned short* __restrict__ ptsTbf,
                                             const float* __restrict__ xyz,
                                             const float* __restrict__ nxyz,
                                             const int* __restrict__ idx,
                                             const unsigned short* __restrict__ w1f,
                                             const float* __restrict__ bn1c,
                                             const unsigned short* __restrict__ w2f,
                                             const float* __restrict__ b2,
                                             const float* __restrict__ g2,
                                             float* __restrict__ part2,
                                             float* __restrict__ valv) {
  __shared__ unsigned short zs[64 * 128];   // gather tile, then z1 tile (both swz (row&7)<<4)
  __shared__ float bns[256];
  int t = threadIdx.x;
  int m0 = blockIdx.x * 64;
  int b = m0 >> 15;
  int lane = t & 63, w = t >> 6;
  bns[t] = bn1c[t];
  bf16x8 b1frag[2][3];
  {
    const uint4* wp = reinterpret_cast<const uint4*>(w1f);
#pragma unroll
    for (int nt = 0; nt < 2; ++nt)
#pragma unroll
      for (int ks = 0; ks < 3; ++ks)
        b1frag[nt][ks] = __builtin_bit_cast(bf16x8, wp[((w * 2 + nt) * 3 + ks) * 64 + lane]);
  }
  stage_gather(zs, ptsTbf, xyz, nxyz, idx, m0, b, t);
  __syncthreads();
  int r15 = lane & 15, rhi = lane >> 4;
  f32x4 acc1[4][2];
#pragma unroll
  for (int mt = 0; mt < 4; ++mt)
#pragma unroll
    for (int nt = 0; nt < 2; ++nt) acc1[mt][nt] = f32x4{0.f, 0.f, 0.f, 0.f};
  {
    const char* zc = reinterpret_cast<const char*>(zs);
#pragma unroll
    for (int mt = 0; mt < 4; ++mt) {
      int row = mt * 16 + r15;
      bf16x8 af[3];
#pragma unroll
      for (int ks = 0; ks < 3; ++ks)
        af[ks] = __builtin_bit_cast(
            bf16x8, *reinterpret_cast<const uint4*>(
                        zc + ((row * 256 + ks * 64 + rhi * 16) ^ ((row & 7) << 4))));
#pragma unroll
      for (int nt = 0; nt < 2; ++nt)
#pragma unroll
        for (int ks = 0; ks < 3; ++ks)
          acc1[mt][nt] = __builtin_amdgcn_mfma_f32_16x16x32_bf16(af[ks], b1frag[nt][ks],
                                                                 acc1[mt][nt], 0, 0, 0);
    }
  }
  __syncthreads();   // gather tile reads done; reuse zs for z1
  {
    char* zcw = reinterpret_cast<char*>(zs);
#pragma unroll
    for (int nt = 0; nt < 2; ++nt) {
      int col = w * 32 + nt * 16 + r15;
      float a = bns[col], c = bns[128 + col];
#pragma unroll
      for (int mt = 0; mt < 4; ++mt)
#pragma unroll
        for (int rg = 0; rg < 4; ++rg) {
          int row = mt * 16 + rhi * 4 + rg;
          float z = fmaxf(0.f, a * acc1[mt][nt][rg] + c);
          *reinterpret_cast<unsigned short*>(
              zcw + ((row * 256 + col * 2) ^ ((row & 7) << 4))) = f2bf(z);
        }
    }
  }
  __syncthreads();
  // W2 fragments (loaded after acc1 is dead to cap VGPR)
  bf16x8 b2frag[4][4];
  {
    const uint4* wp = reinterpret_cast<const uint4*>(w2f) + (size_t)(w * 4) * 4 * 64 + lane;
#pragma unroll
    for (int nt = 0; nt < 4; ++nt)
#pragma unroll
      for (int ks = 0; ks < 4; ++ks)
        b2frag[nt][ks] = __builtin_bit_cast(bf16x8, wp[(nt * 4 + ks) * 64]);
  }
  f32x4 acc[4][4];
#pragma unroll
  for (int mt = 0; mt < 4; ++mt)
#pragma unroll
    for (int nt = 0; nt < 4; ++nt) acc[mt][nt] = f32x4{0.f, 0.f, 0.f, 0.f};
  {
    const char* zc = reinterpret_cast<const char*>(zs);
#pragma unroll
    for (int mt = 0; mt < 4; ++mt) {
      int row = mt * 16 + r15;
      bf16x8 af[4];
#pragma unroll
      for (int ks = 0; ks < 4; ++ks)
        af[ks] = __builtin_bit_cast(
            bf16x8, *reinterpret_cast<const uint4*>(
                        zc + ((row * 256 + ks * 64 + rhi * 16) ^ ((row & 7) << 4))));
#pragma unroll
      for (int nt = 0; nt < 4; ++nt)
#pragma unroll
        for (int ks = 0; ks < 4; ++ks)
          acc[mt][nt] = __builtin_amdgcn_mfma_f32_16x16x32_bf16(af[ks], b2frag[nt][ks],
                                                                acc[mt][nt], 0, 0, 0);
    }
  }
  int wn0 = w * 64;
  int q0 = m0 >> 5;   // 2 queries per block (32 samples each)
#pragma unroll
  for (int nt = 0; nt < 4; ++nt) {
    int col = wn0 + nt * 16 + r15;
    float bv = b2[col];
    bool pos = (g2[col] >= 0.0f);   // sign(a2) == sign(g2), rsqrt > 0
    float s = 0.f, ss = 0.f;
    float mA = -3.0e38f, mB = -3.0e38f, nA = 3.0e38f, nB = 3.0e38f;
#pragma unroll
    for (int mt = 0; mt < 4; ++mt)
#pragma unroll
      for (int rg = 0; rg < 4; ++rg) {
        float v = acc[mt][nt][rg] + bv;
        s += v; ss += v * v;
        if (mt < 2) { mA = fmaxf(mA, v); nA = fminf(nA, v); }
        else        { mB = fmaxf(mB, v); nB = fminf(nB, v); }
      }
    float vA = pos ? mA : nA, vB = pos ? mB : nB;
    s += __shfl_xor(s, 16); s += __shfl_xor(s, 32);
    ss += __shfl_xor(ss, 16); ss += __shfl_xor(ss, 32);
    if (pos) {
      vA = fmaxf(vA, __shfl_xor(vA, 16)); vA = fmaxf(vA, __shfl_xor(vA, 32));
      vB = fmaxf(vB, __shfl_xor(vB, 16)); vB = fmaxf(vB, __shfl_xor(vB, 32));
    } else {
      vA = fminf(vA, __shfl_xor(vA, 16)); vA = fminf(vA, __shfl_xor(vA, 32));
      vB = fminf(vB, __shfl_xor(vB, 16)); vB = fminf(vB, __shfl_xor(vB, 32));
    }
    if (lane < 16) {
      part2[(size_t)blockIdx.x * 512 + col] = s;
      part2[(size_t)blockIdx.x * 512 + 256 + col] = ss;
    }
    if (lane < 32) {
      int q = q0 + (lane >> 4);
      valv[(size_t)q * C2 + col] = (lane < 16) ? vA : vB;
    }
  }
}

// ---------- stats reduce (layer2, stage a only) ----------
__global__ __launch_bounds__(512) void k_red2a(const float* __restrict__ part2,
                                               float* __restrict__ p2b) {
  int t = threadIdx.x, r = blockIdx.x;       // 128 blocks x 32 rows
  float acc = 0.f;
  for (int row = r * 32; row < r * 32 + 32; ++row)
    acc += part2[(size_t)row * 512 + t];
  p2b[r * 512 + t] = acc;
}

// ---------- epilogue: derive bn2 slice from p2b; out = relu(a2*val + c2), transposed ----------
__global__ __launch_bounds__(256) void k_out(const float* __restrict__ valv,
                                             const float* __restrict__ p2b,
                                             const float* __restrict__ g2,
                                             const float* __restrict__ be2,
                                             float* __restrict__ out) {
  __shared__ float tile[64][65];
  __shared__ float sred[256], ssred[256];
  __shared__ float as_[64], cs_[64];
  int b = blockIdx.z, col0 = blockIdx.y * 64, s0 = blockIdx.x * 64;
  int t = threadIdx.x;
  int colL = t & 63, grp = t >> 6;
  {
    int col = col0 + colL;
    float s = 0.f, ss = 0.f;
    for (int row = grp * 32; row < grp * 32 + 32; ++row) {
      s += p2b[row * 512 + col];
      ss += p2b[row * 512 + 256 + col];
    }
    sred[grp * 64 + colL] = s;
    ssred[grp * 64 + colL] = ss;
  }
  __syncthreads();
  if (grp == 0) {
    float S = sred[colL] + sred[64 + colL] + sred[128 + colL] + sred[192 + colL];
    float SS = ssred[colL] + ssred[64 + colL] + ssred[128 + colL] + ssred[192 + colL];
    float mean = S / (float)Mm;
    float var = SS / (float)Mm - mean * mean;
    float a = g2[col0 + colL] * rsqrtf(var + BNEPS);
    as_[colL] = a;
    cs_[colL] = be2[col0 + colL] - mean * a;
  }
  __syncthreads();
  float a = as_[colL], c = cs_[colL];
  int sr = grp;
#pragma unroll
  for (int i = 0; i < 16; ++i) {
    int sl = sr * 16 + i;
    size_t q = (size_t)(b * Sn + s0 + sl);
    float v = valv[q * C2 + col0 + colL];
    tile[colL][sl] = fmaxf(0.f, a * v + c);
  }
  __syncthreads();
  int sl = t & 63, cr = t >> 6;
#pragma unroll
  for (int i = 0; i < 16; ++i) {
    int chl2 = i * 4 + cr;
    out[OUT_XYZ + ((size_t)(b * C2 + col0 + chl2)) * Sn + s0 + sl] = tile[chl2][sl];
  }
}

extern "C" void kernel_launch(void* const* d_in, const int* in_sizes, int n_in,
                              void* d_out, int out_size, void* d_ws, size_t ws_size,
                              hipStream_t stream) {
  (void)in_sizes; (void)n_in; (void)out_size; (void)ws_size;
  const float* xyz  = (const float*)d_in[0];
  const float* pts  = (const float*)d_in[1];
  const float* nxyz = (const float*)d_in[2];
  const float* W1   = (const float*)d_in[3];
  const float* b1   = (const float*)d_in[4];
  const float* g1   = (const float*)d_in[5];
  const float* be1  = (const float*)d_in[6];
  const float* W2   = (const float*)d_in[7];
  const float* b2   = (const float*)d_in[8];
  const float* g2   = (const float*)d_in[9];
  const float* be2  = (const float*)d_in[10];
  float* out = (float*)d_out;
  char* ws = (char*)d_ws;

  int*            idx    = (int*)(ws + OFF_IDX);
  unsigned short* ptsTbf = (unsigned short*)(ws + OFF_PTST);
  float*          part1  = (float*)(ws + OFF_P1);
  float*          part2  = (float*)(ws + OFF_P2);
  float*          p1b    = (float*)(ws + OFF_P1B);
  float*          p2b    = (float*)(ws + OFF_P2B);
  float*          bn1    = (float*)(ws + OFF_BN1);
  unsigned short* w2f    = (unsigned short*)(ws + OFF_W2F);
  unsigned short* w1f    = (unsigned short*)(ws + OFF_W1F);
  float*          valv   = (float*)(ws + OFF_VAL);

  k_knn<<<Qq + 784, 256, 0, stream>>>(xyz, nxyz, idx, pts, W1, W2, ptsTbf, out, w1f, w2f);
  k_mlp1s<<<NB_M1, 256, 0, stream>>>(ptsTbf, xyz, nxyz, idx, w1f, b1, part1);
  k_red1a<<<128, 256, 0, stream>>>(part1, p1b);
  k_red1b<<<1, 256, 0, stream>>>(p1b, b1, g1, be1, bn1);
  k_m2f<<<NB_MLP, 256, 0, stream>>>(ptsTbf, xyz, nxyz, idx, w1f, bn1, w2f, b2, g2, part2, valv);
  k_red2a<<<128, 512, 0, stream>>>(part2, p2b);
  k_out<<<dim3(Sn / 64, C2 / 64, Bn), 256, 0, stream>>>(valv, p2b, g2, be2, out);
}

// Round 18
// 124.675 us; speedup vs baseline: 1.0199x; 1.0199x over previous
//
#include <hip/hip_runtime.h>
#include <stdint.h>

constexpr int Bn = 8, Nn = 4096, Sn = 1024, Cc = 64, KNN = 32, C1 = 128, C2 = 256;
constexpr int Qq = Bn * Sn;     // 8192 queries
constexpr int Mm = Qq * KNN;    // 262144 samples
constexpr int OUT_XYZ = Bn * Sn * 3;  // 24576 floats (output 0)
constexpr float BNEPS = 1e-5f;
constexpr unsigned RSEL = 9;    // sample order statistic -> E[candidates]~72

// ---------- ws layout ----------
constexpr size_t SZ_IDX  = (size_t)Qq * KNN * 4;        // 1 MB
constexpr size_t SZ_PTST = (size_t)Bn * Nn * Cc * 2;    // 4 MB (bf16)
constexpr int    NB_MLP  = Mm / 64;                     // 4096 blocks (m2f)
constexpr int    NB_M1   = Mm / 128;                    // 2048 blocks (mlp1s)
constexpr size_t SZ_P1   = (size_t)NB_M1 * 256 * 4;     // 2 MB
constexpr size_t SZ_P2   = (size_t)NB_MLP * 512 * 4;    // 8 MB
constexpr size_t OFF_IDX  = 0;
constexpr size_t OFF_PTST = OFF_IDX + SZ_IDX;
constexpr size_t OFF_P1   = OFF_PTST + SZ_PTST;
constexpr size_t OFF_P2   = OFF_P1 + SZ_P1;
constexpr size_t OFF_P1B  = OFF_P2 + SZ_P2;
constexpr size_t OFF_P2B  = OFF_P1B + (size_t)128 * 256 * 4;
constexpr size_t OFF_BN1  = OFF_P2B + (size_t)128 * 512 * 4;
constexpr size_t OFF_W2F  = OFF_BN1 + 1024;                  // 64 KB
constexpr size_t OFF_W1F  = OFF_W2F + (size_t)32768 * 2;     // 24 KB
constexpr size_t OFF_VAL  = (OFF_W1F + (size_t)12288 * 2 + 255) & ~(size_t)255;  // extreme: 8 MB

typedef __attribute__((ext_vector_type(8))) __bf16 bf16x8;
typedef __attribute__((ext_vector_type(4))) float f32x4;

__device__ __forceinline__ unsigned short f2bf(float f) {
  unsigned u = __float_as_uint(f);
  u = u + 0x7FFFu + ((u >> 16) & 1u);   // RNE
  return (unsigned short)(u >> 16);
}

// ballot-aggregated histogram add (use only for CLUSTERED bins, e.g. fp exponent)
__device__ __forceinline__ void agg_hist(unsigned* hist, unsigned bin, bool valid, int lane) {
  bool todo = valid;
  while (true) {
    unsigned long long bm = __ballot(todo);
    if (bm == 0ull) break;
    int first = __ffsll(bm) - 1;
    unsigned b = (unsigned)__shfl((int)bin, first);
    unsigned long long m = __ballot(todo && bin == b);
    if (lane == first) atomicAdd(&hist[b], (unsigned)__popcll(m));
    if (todo && bin == b) todo = false;
  }
}

// ---------- kNN (blocks < Qq) + fused prep (blocks >= Qq; outputs consumed only by LATER kernels) ----------
// Distance bits replicate the reference evaluation (norms plain mul/add, dot FMA
// chain, (A+B)-2*dot) under `fp contract(off)`. Threshold U heuristic; fast path
// only if 32<=cnt<=256 (superset proof). Rank on u32 keys (strict-less, tiered
// split); key ties detected via rank-histogram -> block-uniform u64 redo (exact
// top_k tie-break). Fallback: full radix (round-4 proven).
__global__ __launch_bounds__(256) void k_knn(const float* __restrict__ xyz,
                                             const float* __restrict__ nxyz,
                                             int* __restrict__ idxout,
                                             const float* __restrict__ pts,
                                             const float* __restrict__ W1,
                                             const float* __restrict__ W2,
                                             unsigned short* __restrict__ ptsTbf,
                                             float* __restrict__ outdst,
                                             unsigned short* __restrict__ w1f,
                                             unsigned short* __restrict__ w2f) {
  int t = threadIdx.x;
  if (blockIdx.x >= (unsigned)Qq) {          // ---- prep branch ----
    int blk = blockIdx.x - Qq;
    if (blk < 512) {                         // points [B,C,N] f32 -> [B,N,C] bf16
      __shared__ float tile[64][65];
      int b = blk >> 6, n0 = (blk & 63) * 64;
      int cl = t & 63, rw = t >> 6;
#pragma unroll
      for (int i = 0; i < 16; ++i) {
        int c = i * 4 + rw;
        tile[cl][c] = pts[((size_t)b * Cc + c) * Nn + n0 + cl];
      }
      __syncthreads();
#pragma unroll
      for (int i = 0; i < 16; ++i) {
        int nf = i * 4 + rw;
        ptsTbf[((size_t)b * Nn + n0 + nf) * Cc + cl] = f2bf(tile[nf][cl]);
      }
    } else if (blk < 608) {                  // copy new_xyz to output 0
      int i = t + (blk - 512) * 256;
      if (i < OUT_XYZ) outdst[i] = nxyz[i];
    } else if (blk < 656) {                  // W1 -> bf16 B-frags, K pad 96
      int u = t + (blk - 608) * 256;
      int j = u & 7, lane = (u >> 3) & 63, rest = u >> 9;
      int ks = rest % 3, nt = rest / 3;
      int ch = nt * 16 + (lane & 15);
      int k = ks * 32 + (lane >> 4) * 8 + j;
      w1f[u] = (k < 70) ? f2bf(W1[ch * 70 + k]) : (unsigned short)0;
    } else {                                 // W2 -> bf16 B-frags
      int u = t + (blk - 656) * 256;
      int j = u & 7, lane = (u >> 3) & 63, ks = (u >> 9) & 3, ntile = u >> 11;
      int col = ntile * 16 + (lane & 15);
      int k = ks * 32 + (lane >> 4) * 8 + j;
      w2f[u] = f2bf(W2[col * C1 + k]);
    }
    return;
  }
  // ---- knn branch ----
  int q = blockIdx.x, b = q >> 10;
  int lane = t & 63, w = t >> 6;
  const float4* xb4 = reinterpret_cast<const float4*>(xyz + (size_t)b * Nn * 3);
  float qx = nxyz[q * 3 + 0], qy = nxyz[q * 3 + 1], qz = nxyz[q * 3 + 2];
  unsigned key[16];
  {
#pragma clang fp contract(off)
    float sqq = (qx * qx + qy * qy) + qz * qz;
#pragma unroll
    for (int h = 0; h < 2; ++h) {            // 2 half-chunks of 8 points
      float fl[24];
#pragma unroll
      for (int j = 0; j < 6; ++j) {
        float4 v = xb4[t * 12 + h * 6 + j];
        fl[4 * j + 0] = v.x; fl[4 * j + 1] = v.y; fl[4 * j + 2] = v.z; fl[4 * j + 3] = v.w;
      }
#pragma unroll
      for (int i = 0; i < 8; ++i) {
        float xl = fl[3 * i], yl = fl[3 * i + 1], zl = fl[3 * i + 2];
        float sqp = (xl * xl + yl * yl) + zl * zl;
        float dot = __builtin_fmaf(qz, zl, __builtin_fmaf(qy, yl, qx * xl));
        float d = (sqq + sqp) - 2.0f * dot;
        unsigned u = __float_as_uint(d);
        key[h * 8 + i] = (u & 0x80000000u) ? ~u : (u | 0x80000000u);   // monotone map
      }
    }
  }
  __shared__ unsigned long long buf64[256];
  __shared__ unsigned hist[256];
  __shared__ unsigned hist2[256];
  __shared__ unsigned wsum[4];
  __shared__ unsigned sel_bin, sel_off, cnt, ovf, thrU, tieflag;
  __shared__ unsigned eqcnt;
  __shared__ int eqbuf[128];

  unsigned s0 = key[0], s1 = key[8];   // samples: points 16t and 16t+8
  hist[t] = 0;
  hist2[t] = 0;
  if (t == 0) { cnt = 0; ovf = 0; thrU = 0xFFFFFFFFu; tieflag = 0; }
  __syncthreads();
  // S1: top byte of samples (exponent-clustered -> aggregated adds)
  agg_hist(hist, s0 >> 24, true, lane);
  agg_hist(hist, s1 >> 24, true, lane);
  __syncthreads();
  {
    unsigned h = hist[t], v = h;
#pragma unroll
    for (int off = 1; off < 64; off <<= 1) {
      unsigned o = __shfl_up(v, off);
      if (lane >= off) v += o;
    }
    if (lane == 63) wsum[w] = v;
    __syncthreads();
    unsigned woff = 0;
    for (int ww = 0; ww < w; ++ww) woff += wsum[ww];
    v += woff;
    unsigned vex = v - h;
    if (vex < RSEL && RSEL <= v) { sel_bin = (unsigned)t; sel_off = RSEL - vex; }
    __syncthreads();
  }
  unsigned sbin = sel_bin, srem = sel_off;
  // S2: byte 2 of samples in sbin (uniform bins -> plain atomics)
  if ((s0 >> 24) == sbin) atomicAdd(&hist2[(s0 >> 16) & 255u], 1u);
  if ((s1 >> 24) == sbin) atomicAdd(&hist2[(s1 >> 16) & 255u], 1u);
  __syncthreads();
  {
    unsigned h = hist2[t], v = h;
#pragma unroll
    for (int off = 1; off < 64; off <<= 1) {
      unsigned o = __shfl_up(v, off);
      if (lane >= off) v += o;
    }
    if (lane == 63) wsum[w] = v;
    __syncthreads();
    unsigned woff = 0;
    for (int ww = 0; ww < w; ++ww) woff += wsum[ww];
    v += woff;
    unsigned vex = v - h;
    if (vex < srem && srem <= v) {
      unsigned p16 = (sbin << 8) | (unsigned)t;
      thrU = (p16 >= 0xFFFFu) ? 0xFFFFFFFFu : ((p16 + 1u) << 16);
    }
    __syncthreads();
  }
  unsigned U = thrU;
  // compact candidates (key < U), ballot-aggregated
#pragma unroll
  for (int i = 0; i < 16; ++i) {
    bool take = key[i] < U;
    unsigned long long m = __ballot(take);
    if (m == 0ull) continue;
    unsigned base = 0;
    if (lane == 0) base = atomicAdd(&cnt, (unsigned)__popcll(m));
    base = (unsigned)__shfl((int)base, 0);
    if (take) {
      unsigned off = base + (unsigned)__popcll(m & ((1ull << lane) - 1ull));
      if (off < 256u)
        buf64[off] = ((unsigned long long)key[i] << 32) | (unsigned)(t * 16 + i);
      else
        ovf = 1;
    }
  }
  __syncthreads();
  unsigned ncnt = cnt;
  if (!ovf && ncnt >= (unsigned)KNN && ncnt <= 256u) {
    int nc = (int)ncnt;
    const unsigned* keyhw = reinterpret_cast<const unsigned*>(buf64);  // [2i]=idx, [2i+1]=key
    int r = 0;
    bool own = false;
    int cid = 0;
    if (nc <= 64) {
      // 4-way wave-split: candidate = lane; wave w scans source lanes [16w,16w+16)
      unsigned mykey = (lane < nc) ? keyhw[2 * lane + 1] : 0xFFFFFFFFu;
      int partial = 0;
      int base = w * 16;
#pragma unroll
      for (int ii = 0; ii < 16; ++ii) {
        int i = base + ii;
        bool inr = (i < nc);
        unsigned ok = (unsigned)__builtin_amdgcn_readlane((int)mykey, i);
        partial += (inr && ok < mykey);
      }
      hist[w * 64 + lane] = (unsigned)partial;
      __syncthreads();
      if (t < 64) {
        r = (int)(hist[t] + hist[64 + t] + hist[128 + t] + hist[192 + t]);
        cid = t;
        own = (t < nc);
      }
    } else if (nc <= 128) {
      // 2-way split: candidate = t&127; half t>>7 scans its 64-chunk
      cid = t & 127;
      bool haveC = (cid < nc);
      unsigned mykey = haveC ? keyhw[2 * cid + 1] : 0xFFFFFFFFu;
      int partial = 0;
      int c = t >> 7;
      if (c * 64 < nc) {
        int ci = c * 64 + lane;
        unsigned bk = (ci < nc) ? keyhw[2 * ci + 1] : 0xFFFFFFFFu;
#pragma unroll
        for (int i = 0; i < 64; ++i) {
          unsigned ok = (unsigned)__builtin_amdgcn_readlane((int)bk, i);
          partial += (ok < mykey);
        }
      }
      hist[t] = (unsigned)partial;
      __syncthreads();
      if (t < 128) {
        r = (int)(hist[t] + hist[t + 128]);
        own = haveC;
      }
    } else {
      // full: candidate = t, scan all chunks
      cid = t;
      bool haveC = (t < nc);
      unsigned mykey = haveC ? keyhw[2 * t + 1] : 0xFFFFFFFFu;
      int nchunk = (nc + 63) >> 6;
      for (int c = 0; c < nchunk; ++c) {
        int ci = c * 64 + lane;
        unsigned bk = (ci < nc) ? keyhw[2 * ci + 1] : 0xFFFFFFFFu;
#pragma unroll
        for (int i = 0; i < 64; ++i) {
          unsigned ok = (unsigned)__builtin_amdgcn_readlane((int)bk, i);
          r += (ok < mykey);
        }
      }
      own = haveC;
    }
    // tie detection: strict-less u32 ranks collide iff keys tie
    hist2[t] = 0;
    __syncthreads();
    if (own) atomicAdd(&hist2[r], 1u);
    __syncthreads();
    if (hist2[t] > 1u) tieflag = 1;
    __syncthreads();
    if (tieflag) {   // rare: exact u64 redo, generic (candidate = t)
      bool own2 = (t < nc);
      unsigned long long my64 = own2 ? buf64[t] : ~0ull;
      int rr = 0;
      int nchunk = (nc + 63) >> 6;
      for (int c = 0; c < nchunk; ++c) {
        int ci = c * 64 + lane;
        unsigned long long v = (ci < nc) ? buf64[ci] : ~0ull;
        unsigned vlo = (unsigned)v, vhi = (unsigned)(v >> 32);
#pragma unroll
        for (int i = 0; i < 64; ++i) {
          unsigned olo = (unsigned)__builtin_amdgcn_readlane((int)vlo, i);
          unsigned ohi = (unsigned)__builtin_amdgcn_readlane((int)vhi, i);
          unsigned long long o = ((unsigned long long)ohi << 32) | olo;
          rr += (o < my64);
        }
      }
      if (own2 && rr < KNN) idxout[q * KNN + rr] = (int)keyhw[2 * t];
    } else {
      if (own && r < KNN) idxout[q * KNN + r] = (int)keyhw[2 * cid];
    }
  } else {
    // fallback: full 4-pass radix (round-4 proven path)
    unsigned prefix = 0, remaining = (unsigned)KNN;
    if (t == 0) { cnt = 0; eqcnt = 0; }
#pragma unroll
    for (int shift = 24; shift >= 0; shift -= 8) {
      hist[t] = 0;
      __syncthreads();
      unsigned himask = (shift == 24) ? 0u : (0xFFFFFFFFu << ((shift + 8) & 31));
#pragma unroll
      for (int i = 0; i < 16; ++i)
        if ((key[i] & himask) == prefix)
          atomicAdd(&hist[(key[i] >> shift) & 255], 1u);
      __syncthreads();
      unsigned h = hist[t], v = h;
#pragma unroll
      for (int off = 1; off < 64; off <<= 1) {
        unsigned o = __shfl_up(v, off);
        if (lane >= off) v += o;
      }
      if (lane == 63) wsum[w] = v;
      __syncthreads();
      unsigned woff = 0;
      for (int ww = 0; ww < w; ++ww) woff += wsum[ww];
      v += woff;
      unsigned vex = v - h;
      if (vex < remaining && remaining <= v) { sel_bin = (unsigned)t; sel_off = vex; }
      __syncthreads();
      prefix |= sel_bin << shift;
      remaining -= sel_off;
    }
#pragma unroll
    for (int i = 0; i < 16; ++i) {
      int p = t * 16 + i;
      if (key[i] < prefix) {
        unsigned pos = atomicAdd(&cnt, 1u);
        idxout[q * KNN + pos] = p;
      } else if (key[i] == prefix) {
        unsigned e = atomicAdd(&eqcnt, 1u);
        if (e < 128u) eqbuf[e] = p;
      }
    }
    __syncthreads();
    if (t == 0) {
      int n = (int)min(eqcnt, 128u);
      for (int a = 1; a < n; ++a) {
        int x = eqbuf[a], bi = a - 1;
        while (bi >= 0 && eqbuf[bi] > x) { eqbuf[bi + 1] = eqbuf[bi]; --bi; }
        eqbuf[bi + 1] = x;
      }
      int base = (int)cnt;
      for (int j = 0; j < (int)remaining; ++j) idxout[q * KNN + base + j] = eqbuf[j];
    }
  }
}

// ---------- staging: 64-row gather tile -> zs (swz (j&7)<<4), 4 loaders/row ----------
__device__ __forceinline__ void stage_gather(unsigned short* zs,
                                             const unsigned short* __restrict__ ptsTbf,
                                             const float* __restrict__ xyz,
                                             const float* __restrict__ nxyz,
                                             const int* __restrict__ idx,
                                             int m0, int b, int t) {
  int j = t >> 2, part = t & 3;
  int m = m0 + j;
  int pid = idx[m];
  const uint4* src =
      reinterpret_cast<const uint4*>(ptsTbf + ((size_t)b * Nn + pid) * Cc + part * 16);
  char* zc = reinterpret_cast<char*>(zs);
  int base = j * 256, swz = (j & 7) << 4;
  uint4 s0 = src[0], s1 = src[1];
  *reinterpret_cast<uint4*>(zc + ((base + part * 32) ^ swz)) = s0;
  *reinterpret_cast<uint4*>(zc + ((base + part * 32 + 16) ^ swz)) = s1;
  uint4 ex = make_uint4(0u, 0u, 0u, 0u);
  if (part == 0) {
    const float* xp = xyz + ((size_t)b * Nn + pid) * 3;
    int s = (m >> 5) & (Sn - 1);
    const float* qp = nxyz + (size_t)(b * Sn + s) * 3;
    ex.x = (unsigned)f2bf(xp[0]) | ((unsigned)f2bf(xp[1]) << 16);
    ex.y = (unsigned)f2bf(xp[2]) | ((unsigned)f2bf(qp[0]) << 16);
    ex.z = (unsigned)f2bf(qp[1]) | ((unsigned)f2bf(qp[2]) << 16);
  }
  *reinterpret_cast<uint4*>(zc + ((base + (8 + part) * 16) ^ swz)) = ex;
}

// ---------- staging: 128-row gather tile, 2 loaders/row ----------
__device__ __forceinline__ void stage_gather128(unsigned short* zs,
                                                const unsigned short* __restrict__ ptsTbf,
                                                const float* __restrict__ xyz,
                                                const float* __restrict__ nxyz,
                                                const int* __restrict__ idx,
                                                int m0, int b, int t) {
  int j = t >> 1, part = t & 1;
  int m = m0 + j;
  int pid = idx[m];
  const uint4* src =
      reinterpret_cast<const uint4*>(ptsTbf + ((size_t)b * Nn + pid) * Cc + part * 32);
  char* zc = reinterpret_cast<char*>(zs);
  int base = j * 256, swz = (j & 7) << 4;
#pragma unroll
  for (int u = 0; u < 4; ++u)
    *reinterpret_cast<uint4*>(zc + ((base + part * 64 + u * 16) ^ swz)) = src[u];
  if (part == 0) {
    uint4 ex = make_uint4(0u, 0u, 0u, 0u);
    const float* xp = xyz + ((size_t)b * Nn + pid) * 3;
    int s = (m >> 5) & (Sn - 1);
    const float* qp = nxyz + (size_t)(b * Sn + s) * 3;
    ex.x = (unsigned)f2bf(xp[0]) | ((unsigned)f2bf(xp[1]) << 16);
    ex.y = (unsigned)f2bf(xp[2]) | ((unsigned)f2bf(qp[0]) << 16);
    ex.z = (unsigned)f2bf(qp[1]) | ((unsigned)f2bf(qp[2]) << 16);
    *reinterpret_cast<uint4*>(zc + ((base + 128) ^ swz)) = ex;
    uint4 z0 = make_uint4(0u, 0u, 0u, 0u);
    *reinterpret_cast<uint4*>(zc + ((base + 144) ^ swz)) = z0;
  } else {
    uint4 z0 = make_uint4(0u, 0u, 0u, 0u);
    *reinterpret_cast<uint4*>(zc + ((base + 160) ^ swz)) = z0;
    *reinterpret_cast<uint4*>(zc + ((base + 176) ^ swz)) = z0;
  }
}

// ---------- layer1 stats-only (128-row tile): gather + W1 MFMA -> sum/sumsq partials ----------
__global__ __launch_bounds__(256) void k_mlp1s(const unsigned short* __restrict__ ptsTbf,
                                               const float* __restrict__ xyz,
                                               const float* __restrict__ nxyz,
                                               const int* __restrict__ idx,
                                               const unsigned short* __restrict__ w1f,
                                               const float* __restrict__ b1,
                                               float* __restrict__ part1) {
  __shared__ unsigned short zs[128 * 128];   // 32 KB
  int t = threadIdx.x;
  int m0 = blockIdx.x * 128;
  int b = m0 >> 15;
  int lane = t & 63, w = t >> 6;
  bf16x8 bfrag[2][3];
  {
    const uint4* wp = reinterpret_cast<const uint4*>(w1f);
#pragma unroll
    for (int nt = 0; nt < 2; ++nt)
#pragma unroll
      for (int ks = 0; ks < 3; ++ks)
        bfrag[nt][ks] = __builtin_bit_cast(bf16x8, wp[((w * 2 + nt) * 3 + ks) * 64 + lane]);
  }
  stage_gather128(zs, ptsTbf, xyz, nxyz, idx, m0, b, t);
  __syncthreads();
  f32x4 acc[8][2];
#pragma unroll
  for (int mt = 0; mt < 8; ++mt)
#pragma unroll
    for (int nt = 0; nt < 2; ++nt) acc[mt][nt] = f32x4{0.f, 0.f, 0.f, 0.f};
  int r15 = lane & 15, rhi = lane >> 4;
  const char* zc = reinterpret_cast<const char*>(zs);
#pragma unroll
  for (int mt = 0; mt < 8; ++mt) {
    int row = mt * 16 + r15;
    bf16x8 af[3];
#pragma unroll
    for (int ks = 0; ks < 3; ++ks)
      af[ks] = __builtin_bit_cast(
          bf16x8, *reinterpret_cast<const uint4*>(
                      zc + ((row * 256 + ks * 64 + rhi * 16) ^ ((row & 7) << 4))));
#pragma unroll
    for (int nt = 0; nt < 2; ++nt)
#pragma unroll
      for (int ks = 0; ks < 3; ++ks)
        acc[mt][nt] =
            __builtin_amdgcn_mfma_f32_16x16x32_bf16(af[ks], bfrag[nt][ks], acc[mt][nt], 0, 0, 0);
  }
#pragma unroll
  for (int nt = 0; nt < 2; ++nt) {
    int col = w * 32 + nt * 16 + r15;
    float bv = b1[col];
    float s = 0.f, ss = 0.f;
#pragma unroll
    for (int mt = 0; mt < 8; ++mt)
#pragma unroll
      for (int rg = 0; rg < 4; ++rg) {
        float v = acc[mt][nt][rg] + bv;
        s += v; ss += v * v;
      }
    s += __shfl_xor(s, 16); s += __shfl_xor(s, 32);
    ss += __shfl_xor(ss, 16); ss += __shfl_xor(ss, 32);
    if (lane < 16) {
      part1[(size_t)blockIdx.x * 256 + col] = s;
      part1[(size_t)blockIdx.x * 256 + 128 + col] = ss;
    }
  }
}

// ---------- stats reduce (layer1) ----------
__global__ __launch_bounds__(256) void k_red1a(const float* __restrict__ part1,
                                               float* __restrict__ p1b) {
  int t = threadIdx.x, r = blockIdx.x;       // 128 blocks x 16 rows
  float acc = 0.f;
  for (int row = r * 16; row < r * 16 + 16; ++row)
    acc += part1[(size_t)row * 256 + t];
  p1b[r * 256 + t] = acc;
}
// bn1[t] = a; bn1[128+t] = a*b1 + be1 - mean*a  (b1 folded so fused kernel skips it)
__global__ __launch_bounds__(256) void k_red1b(const float* __restrict__ p1b,
                                               const float* __restrict__ b1,
                                               const float* __restrict__ g1,
                                               const float* __restrict__ be1,
                                               float* __restrict__ bn1) {
  __shared__ float lds[256];
  int t = threadIdx.x;
  float acc = 0.f;
  for (int row = 0; row < 128; ++row) acc += p1b[row * 256 + t];
  lds[t] = acc;
  __syncthreads();
  if (t < 128) {
    float sum = lds[t], ss = lds[128 + t];
    float mean = sum / (float)Mm;
    float var = ss / (float)Mm - mean * mean;
    float a = g1[t] * rsqrtf(var + BNEPS);
    bn1[t] = a;
    bn1[128 + t] = a * b1[t] + (be1[t] - mean * a);
  }
}

// ---------- fused layer1+layer2: gather -> W1 MFMA -> BN1+relu -> W2 MFMA -> stats+extreme ----------
__global__ __launch_bounds__(256) void k_m2f(const unsigned short* __restrict__ ptsTbf,
                                             const float* __restrict__ xyz,
                                             const float* __restrict__ nxyz,
                                             const int* __restrict__ idx,
                                             const unsigned short* __restrict__ w1f,
                                             const float* __restrict__ bn1c,
                                             const unsigned short* __restrict__ w2f,
                                             const float* __restrict__ b2,
                                             const float* __restrict__ g2,
                                             float* __restrict__ part2,
                                             float* __restrict__ valv) {
  __shared__ unsigned short zs[64 * 128];   // gather tile, then z1 tile (both swz (row&7)<<4)
  __shared__ float bns[256];
  int t = threadIdx.x;
  int m0 = blockIdx.x * 64;
  int b = m0 >> 15;
  int lane = t & 63, w = t >> 6;
  bns[t] = bn1c[t];
  bf16x8 b1frag[2][3];
  {
    const uint4* wp = reinterpret_cast<const uint4*>(w1f);
#pragma unroll
    for (int nt = 0; nt < 2; ++nt)
#pragma unroll
      for (int ks = 0; ks < 3; ++ks)
        b1frag[nt][ks] = __builtin_bit_cast(bf16x8, wp[((w * 2 + nt) * 3 + ks) * 64 + lane]);
  }
  stage_gather(zs, ptsTbf, xyz, nxyz, idx, m0, b, t);
  __syncthreads();
  int r15 = lane & 15, rhi = lane >> 4;
  f32x4 acc1[4][2];
#pragma unroll
  for (int mt = 0; mt < 4; ++mt)
#pragma unroll
    for (int nt = 0; nt < 2; ++nt) acc1[mt][nt] = f32x4{0.f, 0.f, 0.f, 0.f};
  {
    const char* zc = reinterpret_cast<const char*>(zs);
#pragma unroll
    for (int mt = 0; mt < 4; ++mt) {
      int row = mt * 16 + r15;
      bf16x8 af[3];
#pragma unroll
      for (int ks = 0; ks < 3; ++ks)
        af[ks] = __builtin_bit_cast(
            bf16x8, *reinterpret_cast<const uint4*>(
                        zc + ((row * 256 + ks * 64 + rhi * 16) ^ ((row & 7) << 4))));
#pragma unroll
      for (int nt = 0; nt < 2; ++nt)
#pragma unroll
        for (int ks = 0; ks < 3; ++ks)
          acc1[mt][nt] = __builtin_amdgcn_mfma_f32_16x16x32_bf16(af[ks], b1frag[nt][ks],
                                                                 acc1[mt][nt], 0, 0, 0);
    }
  }
  __syncthreads();   // gather tile reads done; reuse zs for z1
  {
    char* zcw = reinterpret_cast<char*>(zs);
#pragma unroll
    for (int nt = 0; nt < 2; ++nt) {
      int col = w * 32 + nt * 16 + r15;
      float a = bns[col], c = bns[128 + col];
#pragma unroll
      for (int mt = 0; mt < 4; ++mt)
#pragma unroll
        for (int rg = 0; rg < 4; ++rg) {
          int row = mt * 16 + rhi * 4 + rg;
          float z = fmaxf(0.f, a * acc1[mt][nt][rg] + c);
          *reinterpret_cast<unsigned short*>(
              zcw + ((row * 256 + col * 2) ^ ((row & 7) << 4))) = f2bf(z);
        }
    }
  }
  __syncthreads();
  // W2 fragments (loaded after acc1 is dead to cap VGPR)
  bf16x8 b2frag[4][4];
  {
    const uint4* wp = reinterpret_cast<const uint4*>(w2f) + (size_t)(w * 4) * 4 * 64 + lane;
#pragma unroll
    for (int nt = 0; nt < 4; ++nt)
#pragma unroll
      for (int ks = 0; ks < 4; ++ks)
        b2frag[nt][ks] = __builtin_bit_cast(bf16x8, wp[(nt * 4 + ks) * 64]);
  }
  f32x4 acc[4][4];
#pragma unroll
  for (int mt = 0; mt < 4; ++mt)
#pragma unroll
    for (int nt = 0; nt < 4; ++nt) acc[mt][nt] = f32x4{0.f, 0.f, 0.f, 0.f};
  {
    const char* zc = reinterpret_cast<const char*>(zs);
#pragma unroll
    for (int mt = 0; mt < 4; ++mt) {
      int row = mt * 16 + r15;
      bf16x8 af[4];
#pragma unroll
      for (int ks = 0; ks < 4; ++ks)
        af[ks] = __builtin_bit_cast(
            bf16x8, *reinterpret_cast<const uint4*>(
                        zc + ((row * 256 + ks * 64 + rhi * 16) ^ ((row & 7) << 4))));
#pragma unroll
      for (int nt = 0; nt < 4; ++nt)
#pragma unroll
        for (int ks = 0; ks < 4; ++ks)
          acc[mt][nt] = __builtin_amdgcn_mfma_f32_16x16x32_bf16(af[ks], b2frag[nt][ks],
                                                                acc[mt][nt], 0, 0, 0);
    }
  }
  int wn0 = w * 64;
  int q0 = m0 >> 5;   // 2 queries per block (32 samples each)
#pragma unroll
  for (int nt = 0; nt < 4; ++nt) {
    int col = wn0 + nt * 16 + r15;
    float bv = b2[col];
    bool pos = (g2[col] >= 0.0f);   // sign(a2) == sign(g2), rsqrt > 0
    float s = 0.f, ss = 0.f;
    float mA = -3.0e38f, mB = -3.0e38f, nA = 3.0e38f, nB = 3.0e38f;
#pragma unroll
    for (int mt = 0; mt < 4; ++mt)
#pragma unroll
      for (int rg = 0; rg < 4; ++rg) {
        float v = acc[mt][nt][rg] + bv;
        s += v; ss += v * v;
        if (mt < 2) { mA = fmaxf(mA, v); nA = fminf(nA, v); }
        else        { mB = fmaxf(mB, v); nB = fminf(nB, v); }
      }
    float vA = pos ? mA : nA, vB = pos ? mB : nB;
    s += __shfl_xor(s, 16); s += __shfl_xor(s, 32);
    ss += __shfl_xor(ss, 16); ss += __shfl_xor(ss, 32);
    if (pos) {
      vA = fmaxf(vA, __shfl_xor(vA, 16)); vA = fmaxf(vA, __shfl_xor(vA, 32));
      vB = fmaxf(vB, __shfl_xor(vB, 16)); vB = fmaxf(vB, __shfl_xor(vB, 32));
    } else {
      vA = fminf(vA, __shfl_xor(vA, 16)); vA = fminf(vA, __shfl_xor(vA, 32));
      vB = fminf(vB, __shfl_xor(vB, 16)); vB = fminf(vB, __shfl_xor(vB, 32));
    }
    if (lane < 16) {
      part2[(size_t)blockIdx.x * 512 + col] = s;
      part2[(size_t)blockIdx.x * 512 + 256 + col] = ss;
    }
    if (lane < 32) {
      int q = q0 + (lane >> 4);
      valv[(size_t)q * C2 + col] = (lane < 16) ? vA : vB;
    }
  }
}

// ---------- stats reduce (layer2, stage a only) ----------
__global__ __launch_bounds__(512) void k_red2a(const float* __restrict__ part2,
                                               float* __restrict__ p2b) {
  int t = threadIdx.x, r = blockIdx.x;       // 128 blocks x 32 rows
  float acc = 0.f;
  for (int row = r * 32; row < r * 32 + 32; ++row)
    acc += part2[(size_t)row * 512 + t];
  p2b[r * 512 + t] = acc;
}

// ---------- epilogue: derive bn2 slice from p2b; out = relu(a2*val + c2), transposed ----------
__global__ __launch_bounds__(256) void k_out(const float* __restrict__ valv,
                                             const float* __restrict__ p2b,
                                             const float* __restrict__ g2,
                                             const float* __restrict__ be2,
                                             float* __restrict__ out) {
  __shared__ float tile[64][65];
  __shared__ float sred[256], ssred[256];
  __shared__ float as_[64], cs_[64];
  int b = blockIdx.z, col0 = blockIdx.y * 64, s0 = blockIdx.x * 64;
  int t = threadIdx.x;
  int colL = t & 63, grp = t >> 6;
  {
    int col = col0 + colL;
    float s = 0.f, ss = 0.f;
    for (int row = grp * 32; row < grp * 32 + 32; ++row) {
      s += p2b[row * 512 + col];
      ss += p2b[row * 512 + 256 + col];
    }
    sred[grp * 64 + colL] = s;
    ssred[grp * 64 + colL] = ss;
  }
  __syncthreads();
  if (grp == 0) {
    float S = sred[colL] + sred[64 + colL] + sred[128 + colL] + sred[192 + colL];
    float SS = ssred[colL] + ssred[64 + colL] + ssred[128 + colL] + ssred[192 + colL];
    float mean = S / (float)Mm;
    float var = SS / (float)Mm - mean * mean;
    float a = g2[col0 + colL] * rsqrtf(var + BNEPS);
    as_[colL] = a;
    cs_[colL] = be2[col0 + colL] - mean * a;
  }
  __syncthreads();
  float a = as_[colL], c = cs_[colL];
  int sr = grp;
#pragma unroll
  for (int i = 0; i < 16; ++i) {
    int sl = sr * 16 + i;
    size_t q = (size_t)(b * Sn + s0 + sl);
    float v = valv[q * C2 + col0 + colL];
    tile[colL][sl] = fmaxf(0.f, a * v + c);
  }
  __syncthreads();
  int sl = t & 63, cr = t >> 6;
#pragma unroll
  for (int i = 0; i < 16; ++i) {
    int chl2 = i * 4 + cr;
    out[OUT_XYZ + ((size_t)(b * C2 + col0 + chl2)) * Sn + s0 + sl] = tile[chl2][sl];
  }
}

extern "C" void kernel_launch(void* const* d_in, const int* in_sizes, int n_in,
                              void* d_out, int out_size, void* d_ws, size_t ws_size,
                              hipStream_t stream) {
  (void)in_sizes; (void)n_in; (void)out_size; (void)ws_size;
  const float* xyz  = (const float*)d_in[0];
  const float* pts  = (const float*)d_in[1];
  const float* nxyz = (const float*)d_in[2];
  const float* W1   = (const float*)d_in[3];
  const float* b1   = (const float*)d_in[4];
  const float* g1   = (const float*)d_in[5];
  const float* be1  = (const float*)d_in[6];
  const float* W2   = (const float*)d_in[7];
  const float* b2   = (const float*)d_in[8];
  const float* g2   = (const float*)d_in[9];
  const float* be2  = (const float*)d_in[10];
  float* out = (float*)d_out;
  char* ws = (char*)d_ws;

  int*            idx    = (int*)(ws + OFF_IDX);
  unsigned short* ptsTbf = (unsigned short*)(ws + OFF_PTST);
  float*          part1  = (float*)(ws + OFF_P1);
  float*          part2  = (float*)(ws + OFF_P2);
  float*          p1b    = (float*)(ws + OFF_P1B);
  float*          p2b    = (float*)(ws + OFF_P2B);
  float*          bn1    = (float*)(ws + OFF_BN1);
  unsigned short* w2f    = (unsigned short*)(ws + OFF_W2F);
  unsigned short* w1f    = (unsigned short*)(ws + OFF_W1F);
  float*          valv   = (float*)(ws + OFF_VAL);

  k_knn<<<Qq + 784, 256, 0, stream>>>(xyz, nxyz, idx, pts, W1, W2, ptsTbf, out, w1f, w2f);
  k_mlp1s<<<NB_M1, 256, 0, stream>>>(ptsTbf, xyz, nxyz, idx, w1f, b1, part1);
  k_red1a<<<128, 256, 0, stream>>>(part1, p1b);
  k_red1b<<<1, 256, 0, stream>>>(p1b, b1, g1, be1, bn1);
  k_m2f<<<NB_MLP, 256, 0, stream>>>(ptsTbf, xyz, nxyz, idx, w1f, bn1, w2f, b2, g2, part2, valv);
  k_red2a<<<128, 512, 0, stream>>>(part2, p2b);
  k_out<<<dim3(Sn / 64, C2 / 64, Bn), 256, 0, stream>>>(valv, p2b, g2, be2, out);
}